// Round 14
// baseline (1449.063 us; speedup 1.0000x reference)
//
#include <hip/hip_runtime.h>
#include <hip/hip_bf16.h>
#include <stdint.h>

#define B_ 128
#define T_ 32
#define S_ 256
#define H_ 1024
#define E_ 1024
#define LOG2E 1.4426950408889634f

typedef __attribute__((ext_vector_type(8))) short short8;
typedef __attribute__((ext_vector_type(4))) float f32x4;
typedef __attribute__((ext_vector_type(2))) float f32x2;

typedef const __attribute__((address_space(1))) unsigned int* gas_ptr;
typedef __attribute__((address_space(3))) unsigned int* las_ptr;

__device__ __forceinline__ void gl_lds16(const void* g, void* l) {
    __builtin_amdgcn_global_load_lds((gas_ptr)g, (las_ptr)l, 16, 0, 0);
}

__device__ __forceinline__ float bf2f(unsigned short u) {
    union { unsigned int i; float f; } v; v.i = ((unsigned int)u) << 16; return v.f;
}
__device__ __forceinline__ unsigned short f2bf(float f) {
    union { float f; unsigned int i; } v; v.f = f;
    unsigned int i = v.i;
    return (unsigned short)((i + 0x7FFFu + ((i >> 16) & 1u)) >> 16);
}
__device__ __forceinline__ unsigned char f2fp8(float f) {
    return (unsigned char)((unsigned int)__builtin_amdgcn_cvt_pk_fp8_f32(f, f, 0, false) & 0xFF);
}
__device__ __forceinline__ float fexp2(float x) { return __builtin_amdgcn_exp2f(x); }
__device__ __forceinline__ float frcp(float x)  { return __builtin_amdgcn_rcpf(x); }
__device__ __forceinline__ float fast_tanh(float x) {
    float e = fexp2(x * (2.0f * LOG2E));
    return 1.0f - 2.0f * frcp(e + 1.0f);
}
__device__ __forceinline__ float fast_sigmoid(float x) {
    return frcp(1.0f + fexp2(-LOG2E * x));
}

// ---------------- flat f32 -> bf16 convert (n multiple of 8) ----------------
__global__ __launch_bounds__(256) void conv_bf16(const float* __restrict__ src,
                                                 unsigned short* __restrict__ dst, long n) {
    long i = ((long)blockIdx.x * 256 + threadIdx.x) * 8;
    if (i >= n) return;
    float4 x = *(const float4*)(src + i);
    float4 y = *(const float4*)(src + i + 4);
    unsigned int w0 = (unsigned int)f2bf(x.x) | ((unsigned int)f2bf(x.y) << 16);
    unsigned int w1 = (unsigned int)f2bf(x.z) | ((unsigned int)f2bf(x.w) << 16);
    unsigned int w2 = (unsigned int)f2bf(y.x) | ((unsigned int)f2bf(y.y) << 16);
    unsigned int w3 = (unsigned int)f2bf(y.z) | ((unsigned int)f2bf(y.w) << 16);
    uint4 o; o.x = w0; o.y = w1; o.z = w2; o.w = w3;
    *(uint4*)(dst + i) = o;
}

// ---------------- flat f32 -> fp8-e4m3 convert (n multiple of 8) ----------------
__global__ __launch_bounds__(256) void conv_fp8(const float* __restrict__ src,
                                                unsigned char* __restrict__ dst, long n) {
    long i = ((long)blockIdx.x * 256 + threadIdx.x) * 8;
    if (i >= n) return;
    float4 x = *(const float4*)(src + i);
    float4 y = *(const float4*)(src + i + 4);
    unsigned int w0 = (unsigned int)__builtin_amdgcn_cvt_pk_fp8_f32(x.x, x.y, 0, false);
    w0 = (unsigned int)__builtin_amdgcn_cvt_pk_fp8_f32(x.z, x.w, (int)w0, true);
    unsigned int w1 = (unsigned int)__builtin_amdgcn_cvt_pk_fp8_f32(y.x, y.y, 0, false);
    w1 = (unsigned int)__builtin_amdgcn_cvt_pk_fp8_f32(y.z, y.w, (int)w1, true);
    uint2 o; o.x = w0; o.y = w1;
    *(uint2*)(dst + i) = o;
}

// ---------------- init h buffers ----------------
__global__ __launch_bounds__(256) void init_h(const float* __restrict__ h0,
                                              float* __restrict__ hbuf,
                                              unsigned short* __restrict__ hbf, int n) {
    int i = blockIdx.x * 256 + threadIdx.x;
    if (i < n) { float v = h0[i]; hbuf[i] = v; hbf[i] = f2bf(v); }
}

// ---------------- tiled transpose+convert+scale: dst[c, r] = bf16(scale*src[r, c]) ----------------
// grid: (C/64, R/64), block 256
__global__ __launch_bounds__(256) void transpose_conv(const float* __restrict__ src, int ldsrc,
                                                      unsigned short* __restrict__ dst, int lddst,
                                                      float scale) {
    __shared__ float tile[64][65];
    int tid = threadIdx.x;
    int c0 = blockIdx.x * 64, r0 = blockIdx.y * 64;
    int tr = tid >> 6, tc = tid & 63;
#pragma unroll
    for (int i = 0; i < 16; i++) {
        int r = i * 4 + tr;
        tile[r][tc] = src[(long)(r0 + r) * ldsrc + c0 + tc];
    }
    __syncthreads();
#pragma unroll
    for (int i = 0; i < 16; i++) {
        int rr = i * 4 + tr;
        dst[(long)(c0 + rr) * lddst + r0 + tc] = f2bf(scale * tile[tc][rr]);
    }
}

// ---------------- tiled transpose+convert+scale to fp8: dst[c, r] = fp8(scale*src[r, c]) ----------------
__global__ __launch_bounds__(256) void transpose_conv_fp8(const float* __restrict__ src, int ldsrc,
                                                          unsigned char* __restrict__ dst, int lddst,
                                                          float scale) {
    __shared__ float tile[64][65];
    int tid = threadIdx.x;
    int c0 = blockIdx.x * 64, r0 = blockIdx.y * 64;
    int tr = tid >> 6, tc = tid & 63;
#pragma unroll
    for (int i = 0; i < 16; i++) {
        int r = i * 4 + tr;
        tile[r][tc] = src[(long)(r0 + r) * ldsrc + c0 + tc];
    }
    __syncthreads();
#pragma unroll
    for (int i = 0; i < 16; i++) {
        int rr = i * 4 + tr;
        dst[(long)(c0 + rr) * lddst + r0 + tc] = f2fp8(scale * tile[tc][rr]);
    }
}

// ---------------- generic 128x128-tile bf16 MFMA GEMM (m97 structure) ----------------
// C[M,N] = A[M,K] @ Bt[N,K]^T ; A,Bt bf16 row-major. bf16 store (+ partStride per z).
// SWZ: XCD-chunked remap (requires (gx*gy)%8==0, z==1).
// grid: (N/128, M/128, ksplit). kLen = K chunk per z-block. partStride in ELEMENTS.
template <int SWZ>
__global__ __launch_bounds__(256) void gemm128(const unsigned short* __restrict__ A, int lda,
                                               const unsigned short* __restrict__ Bt, int ldb,
                                               unsigned short* __restrict__ Cout, int ldc,
                                               int kLen, long partStride) {
    __shared__ unsigned short As[128 * 32];
    __shared__ unsigned short Bs[128 * 32];
    const int tid = threadIdx.x;
    int lin = blockIdx.y * gridDim.x + blockIdx.x;
    if (SWZ) {
        int cpx = (gridDim.x * gridDim.y) >> 3;
        lin = (lin & 7) * cpx + (lin >> 3);
    }
    const int n0 = (lin % gridDim.x) * 128;
    const int m0 = (lin / gridDim.x) * 128;
    const int kStart = blockIdx.z * kLen;
    const int w = tid >> 6, l = tid & 63;
    const int wr = w >> 1, wc = w & 1;

    f32x4 acc[4][4];
#pragma unroll
    for (int i = 0; i < 4; i++)
#pragma unroll
        for (int j = 0; j < 4; j++) acc[i][j] = f32x4{0.f, 0.f, 0.f, 0.f};

    for (int kt = 0; kt < kLen; kt += 32) {
        int k0 = kStart + kt;
#pragma unroll
        for (int i = 0; i < 2; i++) {
            int f = i * 4096 + tid * 16;
            int row = f >> 6;
            int cb = f & 63;
            gl_lds16(A + (long)(m0 + row) * lda + k0 + (cb >> 1), (char*)As + f);
            gl_lds16(Bt + (long)(n0 + row) * ldb + k0 + (cb >> 1), (char*)Bs + f);
        }
        asm volatile("s_waitcnt vmcnt(0)" ::: "memory");
        __syncthreads();
        short8 a[4], b[4];
#pragma unroll
        for (int fi = 0; fi < 4; fi++) {
            a[fi] = *(const short8*)((const char*)As + ((wr * 64 + fi * 16 + (l & 15)) * 32 + ((l >> 4) * 8)) * 2);
            b[fi] = *(const short8*)((const char*)Bs + ((wc * 64 + fi * 16 + (l & 15)) * 32 + ((l >> 4) * 8)) * 2);
        }
#pragma unroll
        for (int fi = 0; fi < 4; fi++)
#pragma unroll
            for (int fj = 0; fj < 4; fj++)
                acc[fi][fj] = __builtin_amdgcn_mfma_f32_16x16x32_bf16(a[fi], b[fj], acc[fi][fj], 0, 0, 0);
        __syncthreads();
    }

    long cz = (long)blockIdx.z * partStride;
#pragma unroll
    for (int fi = 0; fi < 4; fi++)
#pragma unroll
        for (int fj = 0; fj < 4; fj++) {
            int m = m0 + wr * 64 + fi * 16 + ((l >> 4) << 2);
            int n = n0 + wc * 64 + fj * 16 + (l & 15);
#pragma unroll
            for (int r = 0; r < 4; r++)
                (Cout + cz)[(long)(m + r) * ldc + n] = f2bf(acc[fi][fj][r]);
        }
}

// ---------------- fp8 x fp8 128x128-tile GEMM (BK=64), fp8 output (for P) ----------------
// C[M,N] = A[M,K] @ Bt[N,K]^T ; A,Bt fp8-e4m3 row-major. grid (N/128, M/128).
// LDS slot-swizzle (both-sides): global source column pre-swizzled, ds_read swizzled.
template <int SWZ>
__global__ __launch_bounds__(256) void gemm128_f8(const unsigned char* __restrict__ A, int lda,
                                                  const unsigned char* __restrict__ Bt, int ldb,
                                                  unsigned char* __restrict__ Cout, int ldc,
                                                  int kLen) {
    __shared__ unsigned char As[128 * 64];
    __shared__ unsigned char Bs[128 * 64];
    const int tid = threadIdx.x;
    int lin = blockIdx.y * gridDim.x + blockIdx.x;
    if (SWZ) {
        int cpx = (gridDim.x * gridDim.y) >> 3;
        lin = (lin & 7) * cpx + (lin >> 3);
    }
    const int n0 = (lin % gridDim.x) * 128;
    const int m0 = (lin / gridDim.x) * 128;
    const int w = tid >> 6, l = tid & 63;
    const int wr = w >> 1, wc = w & 1;
    const int sx = (l & 6) << 3;            // read-side slot swizzle

    f32x4 acc[4][4];
#pragma unroll
    for (int i = 0; i < 4; i++)
#pragma unroll
        for (int j = 0; j < 4; j++) acc[i][j] = f32x4{0.f, 0.f, 0.f, 0.f};

    for (int k0 = 0; k0 < kLen; k0 += 64) {
#pragma unroll
        for (int i = 0; i < 2; i++) {
            int f = i * 4096 + tid * 16;
            int row = f >> 6;       // 64 B per row
            int cb = (f & 63) ^ ((row & 6) << 3);   // pre-swizzled global column
            gl_lds16(A + (long)(m0 + row) * lda + k0 + cb, (char*)As + f);
            gl_lds16(Bt + (long)(n0 + row) * ldb + k0 + cb, (char*)Bs + f);
        }
        asm volatile("s_waitcnt vmcnt(0)" ::: "memory");
        __syncthreads();
        long a[4][2], b[4][2];
#pragma unroll
        for (int fi = 0; fi < 4; fi++)
#pragma unroll
            for (int ks = 0; ks < 2; ks++) {
                int colb = (ks * 32 + ((l >> 4) * 8)) ^ sx;
                a[fi][ks] = *(const long*)(As + (wr * 64 + fi * 16 + (l & 15)) * 64 + colb);
                b[fi][ks] = *(const long*)(Bs + (wc * 64 + fi * 16 + (l & 15)) * 64 + colb);
            }
#pragma unroll
        for (int fi = 0; fi < 4; fi++)
#pragma unroll
            for (int fj = 0; fj < 4; fj++) {
                acc[fi][fj] = __builtin_amdgcn_mfma_f32_16x16x32_fp8_fp8(a[fi][0], b[fj][0], acc[fi][fj], 0, 0, 0);
                acc[fi][fj] = __builtin_amdgcn_mfma_f32_16x16x32_fp8_fp8(a[fi][1], b[fj][1], acc[fi][fj], 0, 0, 0);
            }
        __syncthreads();
    }

#pragma unroll
    for (int fi = 0; fi < 4; fi++)
#pragma unroll
        for (int fj = 0; fj < 4; fj++) {
            int m = m0 + wr * 64 + fi * 16 + ((l >> 4) << 2);
            int n = n0 + wc * 64 + fj * 16 + (l & 15);
#pragma unroll
            for (int r = 0; r < 4; r++)
                Cout[(long)(m + r) * ldc + n] = f2fp8(acc[fi][fj][r]);
        }
}

// ---------------- ctx gates GEMM (bf16 partial slabs) ----------------
// grid (24, 1, 4): ctx@Wi2^T, M=128, N=3072, K=1024 (256/chunk).
// Writes bf16 partials cpart[z][128][3072].
__global__ __launch_bounds__(256) void ctxgates(const unsigned short* __restrict__ ctxbf,
                                                const unsigned short* __restrict__ Wit2,
                                                unsigned short* __restrict__ cpart) {
    __shared__ unsigned short As[128 * 32];
    __shared__ unsigned short Bs[128 * 32];
    const int tid = threadIdx.x;
    const int n0 = blockIdx.x * 128;
    const int z = blockIdx.z;
    const int kStart = z * 256;
    const int w = tid >> 6, l = tid & 63;
    const int wr = w >> 1, wc = w & 1;

    f32x4 acc[4][4];
#pragma unroll
    for (int i = 0; i < 4; i++)
#pragma unroll
        for (int j = 0; j < 4; j++) acc[i][j] = f32x4{0.f, 0.f, 0.f, 0.f};

    for (int kt = 0; kt < 256; kt += 32) {
        int k0 = kStart + kt;
#pragma unroll
        for (int i = 0; i < 2; i++) {
            int f = i * 4096 + tid * 16;
            int row = f >> 6;
            int cb = f & 63;
            gl_lds16(ctxbf + (long)row * 1024 + k0 + (cb >> 1), (char*)As + f);
            gl_lds16(Wit2 + (long)(n0 + row) * 1024 + k0 + (cb >> 1), (char*)Bs + f);
        }
        asm volatile("s_waitcnt vmcnt(0)" ::: "memory");
        __syncthreads();
        short8 a[4], b[4];
#pragma unroll
        for (int fi = 0; fi < 4; fi++) {
            a[fi] = *(const short8*)((const char*)As + ((wr * 64 + fi * 16 + (l & 15)) * 32 + ((l >> 4) * 8)) * 2);
            b[fi] = *(const short8*)((const char*)Bs + ((wc * 64 + fi * 16 + (l & 15)) * 32 + ((l >> 4) * 8)) * 2);
        }
#pragma unroll
        for (int fi = 0; fi < 4; fi++)
#pragma unroll
            for (int fj = 0; fj < 4; fj++)
                acc[fi][fj] = __builtin_amdgcn_mfma_f32_16x16x32_bf16(a[fi], b[fj], acc[fi][fj], 0, 0, 0);
        __syncthreads();
    }

    unsigned short* C = cpart + (long)z * (128 * 3072);
#pragma unroll
    for (int fi = 0; fi < 4; fi++)
#pragma unroll
        for (int fj = 0; fj < 4; fj++) {
            int m = wr * 64 + fi * 16 + ((l >> 4) << 2);
            int n = n0 + wc * 64 + fj * 16 + (l & 15);
#pragma unroll
            for (int r = 0; r < 4; r++)
                C[(long)(m + r) * 3072 + n] = f2bf(acc[fi][fj][r]);
        }
}

// ---------------- attention: scores (tanh, fp8 P) + partial softmax + partial context (fp8 enc) ----------------
// grid: (8, B), block 256. Each block handles 32 source rows. P8 and q prescaled by 2*log2(e).
// q partials come from hpart[4][128][4096] cols 0..1023.
__global__ __launch_bounds__(256) void attn_kernel(const unsigned char* __restrict__ P8,
                                                   const unsigned char* __restrict__ enc8,
                                                   const unsigned short* __restrict__ hpart,
                                                   const float* __restrict__ V,
                                                   float* __restrict__ pctx,   // [8][B][H]
                                                   float* __restrict__ pml) {  // [8][B][2]
    const int oct = blockIdx.x, b = blockIdx.y;
    const int tid = threadIdx.x, w = tid >> 6, l = tid & 63;
    __shared__ float qs[1024];
    __shared__ float sc[32];
    __shared__ float wgt[32];

    // cooperative q build (sum of 4 bf16 split-K partials, cols 0..1023 of hpart)
    {
        int j = tid * 4;
        float s0 = 0.f, s1 = 0.f, s2 = 0.f, s3 = 0.f;
#pragma unroll
        for (int p = 0; p < 4; p++) {
            ushort4 v = *(const ushort4*)(hpart + (long)p * (128 * 4096) + (long)b * 4096 + j);
            s0 += bf2f(v.x); s1 += bf2f(v.y); s2 += bf2f(v.z); s3 += bf2f(v.w);
        }
        qs[j] = s0; qs[j + 1] = s1; qs[j + 2] = s2; qs[j + 3] = s3;
    }
    __syncthreads();

    float q[16], nv2[16];
    float sv = 0.f;
#pragma unroll
    for (int ii = 0; ii < 4; ii++) {
        float4 qq = *(const float4*)(qs + l * 16 + ii * 4);
        float4 vv = *(const float4*)(V + l * 16 + ii * 4);
        q[ii * 4 + 0] = qq.x; q[ii * 4 + 1] = qq.y; q[ii * 4 + 2] = qq.z; q[ii * 4 + 3] = qq.w;
        nv2[ii * 4 + 0] = -2.f * vv.x; nv2[ii * 4 + 1] = -2.f * vv.y;
        nv2[ii * 4 + 2] = -2.f * vv.z; nv2[ii * 4 + 3] = -2.f * vv.w;
        sv += vv.x + vv.y + vv.z + vv.w;
    }

    const int s0 = oct * 32;
#pragma unroll 2
    for (int ss = 0; ss < 8; ss++) {
        int s = w * 8 + ss;
        const unsigned char* prow = P8 + ((long)(b * S_ + s0 + s)) * H_ + l * 16;
        uint4 pw = *(const uint4*)prow;
        float pv[16];
        {
            f32x2 d;
            d = __builtin_amdgcn_cvt_pk_f32_fp8(pw.x, false); pv[0] = d.x; pv[1] = d.y;
            d = __builtin_amdgcn_cvt_pk_f32_fp8(pw.x, true);  pv[2] = d.x; pv[3] = d.y;
            d = __builtin_amdgcn_cvt_pk_f32_fp8(pw.y, false); pv[4] = d.x; pv[5] = d.y;
            d = __builtin_amdgcn_cvt_pk_f32_fp8(pw.y, true);  pv[6] = d.x; pv[7] = d.y;
            d = __builtin_amdgcn_cvt_pk_f32_fp8(pw.z, false); pv[8] = d.x; pv[9] = d.y;
            d = __builtin_amdgcn_cvt_pk_f32_fp8(pw.z, true);  pv[10] = d.x; pv[11] = d.y;
            d = __builtin_amdgcn_cvt_pk_f32_fp8(pw.w, false); pv[12] = d.x; pv[13] = d.y;
            d = __builtin_amdgcn_cvt_pk_f32_fp8(pw.w, true);  pv[14] = d.x; pv[15] = d.y;
        }
        float acc = sv;
#pragma unroll
        for (int i = 0; i < 16; i++) {
            float x = q[i] + pv[i];             // prescaled by 2*log2e
            float d = frcp(fexp2(x) + 1.0f);
            acc = fmaf(d, nv2[i], acc);
        }
#pragma unroll
        for (int off = 32; off; off >>= 1) acc += __shfl_xor(acc, off);
        if (l == 0) sc[s] = acc;
    }
    __syncthreads();

    // partial softmax over the 32 local scores (each wave redundantly)
    float v = (l < 32) ? sc[l] : -3.4e38f;
    float mx = v;
#pragma unroll
    for (int off = 32; off; off >>= 1) mx = fmaxf(mx, __shfl_xor(mx, off));
    float ex = (l < 32) ? fexp2((v - mx) * LOG2E) : 0.f;
    float ls = ex;
#pragma unroll
    for (int off = 32; off; off >>= 1) ls += __shfl_xor(ls, off);
    if (tid < 32) wgt[tid] = ex;
    if (tid == 0) {
        pml[(oct * 128 + b) * 2 + 0] = mx;
        pml[(oct * 128 + b) * 2 + 1] = ls;
    }
    __syncthreads();

    // partial context: each thread owns 4 columns, 32 source rows (fp8 enc)
    float a0 = 0.f, a1 = 0.f, a2 = 0.f, a3 = 0.f;
    const unsigned char* ebase = enc8 + ((long)(b * S_ + s0)) * H_ + tid * 4;
#pragma unroll 4
    for (int s = 0; s < 32; s++) {
        float ws = wgt[s];
        unsigned int u = *(const unsigned int*)(ebase + (long)s * H_);
        f32x2 lo = __builtin_amdgcn_cvt_pk_f32_fp8(u, false);
        f32x2 hi = __builtin_amdgcn_cvt_pk_f32_fp8(u, true);
        a0 = fmaf(ws, lo.x, a0);
        a1 = fmaf(ws, lo.y, a1);
        a2 = fmaf(ws, hi.x, a2);
        a3 = fmaf(ws, hi.y, a3);
    }
    float* po = pctx + ((long)(oct * 128 + b)) * H_ + tid * 4;
    po[0] = a0; po[1] = a1; po[2] = a2; po[3] = a3;
}

// ---------------- combine the eight context partials -> ctx bf16 ----------------
__global__ __launch_bounds__(256) void combine_ctx(const float* __restrict__ pctx,
                                                   const float* __restrict__ pml,
                                                   unsigned short* __restrict__ ctxbf) {
    int b = blockIdx.x, tid = threadIdx.x;
    float mm[8], ll[8];
    float m = -3.4e38f;
#pragma unroll
    for (int p = 0; p < 8; p++) {
        mm[p] = pml[(p * 128 + b) * 2 + 0];
        ll[p] = pml[(p * 128 + b) * 2 + 1];
        m = fmaxf(m, mm[p]);
    }
    float denom = 0.f, f[8];
#pragma unroll
    for (int p = 0; p < 8; p++) { f[p] = fexp2((mm[p] - m) * LOG2E); denom += f[p] * ll[p]; }
    float inv = frcp(denom);
    float a0 = 0.f, a1 = 0.f, a2 = 0.f, a3 = 0.f;
#pragma unroll
    for (int p = 0; p < 8; p++) {
        float4 c = *(const float4*)(pctx + ((long)(p * 128 + b)) * H_ + tid * 4);
        a0 = fmaf(f[p], c.x, a0); a1 = fmaf(f[p], c.y, a1);
        a2 = fmaf(f[p], c.z, a2); a3 = fmaf(f[p], c.w, a3);
    }
    unsigned short* o = ctxbf + (long)b * H_ + tid * 4;
    o[0] = f2bf(a0 * inv); o[1] = f2bf(a1 * inv); o[2] = f2bf(a2 * inv); o[3] = f2bf(a3 * inv);
}

// ---------------- GRU gate math + state update ----------------
// grid: 128 (one block per batch row), block 256 (4 cols per thread).
// rec partials: hpart[4][128][4096] cols 1024..4095; ctx partials: cpart[4][128][3072].
__global__ __launch_bounds__(256) void gru_update(const unsigned short* __restrict__ cpart,
                                                  const unsigned short* __restrict__ hpart,
                                                  const unsigned short* __restrict__ xg,  // [4096,3072] bf16
                                                  const float* __restrict__ bias,   // [3072]
                                                  float* __restrict__ hbuf,
                                                  unsigned short* __restrict__ hbf,
                                                  float* __restrict__ out, int t) {
    const int m = blockIdx.x;
    const int j = threadIdx.x * 4;
    const unsigned short* xr = xg + ((long)(m * T_ + t)) * 3072;
    ushort4 xz = *(const ushort4*)(xr + j);
    ushort4 xrr = *(const ushort4*)(xr + 1024 + j);
    ushort4 xh = *(const ushort4*)(xr + 2048 + j);
    float gz[4] = {bf2f(xz.x), bf2f(xz.y), bf2f(xz.z), bf2f(xz.w)};
    float gr[4] = {bf2f(xrr.x), bf2f(xrr.y), bf2f(xrr.z), bf2f(xrr.w)};
    float gh[4] = {bf2f(xh.x), bf2f(xh.y), bf2f(xh.z), bf2f(xh.w)};
    float rz[4] = {0, 0, 0, 0}, rr[4] = {0, 0, 0, 0}, rh[4] = {0, 0, 0, 0};
#pragma unroll
    for (int p = 0; p < 4; p++) {
        const unsigned short* hp = hpart + (long)p * (128 * 4096) + (long)m * 4096;
        ushort4 a = *(const ushort4*)(hp + 1024 + j);
        ushort4 bb = *(const ushort4*)(hp + 2048 + j);
        ushort4 c = *(const ushort4*)(hp + 3072 + j);
        rz[0] += bf2f(a.x); rz[1] += bf2f(a.y); rz[2] += bf2f(a.z); rz[3] += bf2f(a.w);
        rr[0] += bf2f(bb.x); rr[1] += bf2f(bb.y); rr[2] += bf2f(bb.z); rr[3] += bf2f(bb.w);
        rh[0] += bf2f(c.x); rh[1] += bf2f(c.y); rh[2] += bf2f(c.z); rh[3] += bf2f(c.w);
    }
#pragma unroll
    for (int p = 0; p < 4; p++) {
        const unsigned short* gp = cpart + (long)p * (128 * 3072) + (long)m * 3072;
        ushort4 a = *(const ushort4*)(gp + j);
        ushort4 bb = *(const ushort4*)(gp + 1024 + j);
        ushort4 c = *(const ushort4*)(gp + 2048 + j);
        gz[0] += bf2f(a.x); gz[1] += bf2f(a.y); gz[2] += bf2f(a.z); gz[3] += bf2f(a.w);
        gr[0] += bf2f(bb.x); gr[1] += bf2f(bb.y); gr[2] += bf2f(bb.z); gr[3] += bf2f(bb.w);
        gh[0] += bf2f(c.x); gh[1] += bf2f(c.y); gh[2] += bf2f(c.z); gh[3] += bf2f(c.w);
    }
    float4 bz = *(const float4*)(bias + j);
    float4 br = *(const float4*)(bias + 1024 + j);
    float4 bh = *(const float4*)(bias + 2048 + j);
    float4 hv = *(const float4*)(hbuf + (long)m * H_ + j);
    float bzf[4] = {bz.x, bz.y, bz.z, bz.w};
    float brf[4] = {br.x, br.y, br.z, br.w};
    float bhf[4] = {bh.x, bh.y, bh.z, bh.w};
    float hf[4] = {hv.x, hv.y, hv.z, hv.w};
    float hn[4];
    ushort4 hb;
#pragma unroll
    for (int c = 0; c < 4; c++) {
        float z = fast_sigmoid(gz[c] + bzf[c] + rz[c]);
        float r = fast_sigmoid(gr[c] + brf[c] + rr[c]);
        float hh = fast_tanh(gh[c] + bhf[c] + r * rh[c]);
        hn[c] = z * hf[c] + (1.0f - z) * hh;
    }
    hb.x = f2bf(hn[0]); hb.y = f2bf(hn[1]); hb.z = f2bf(hn[2]); hb.w = f2bf(hn[3]);
    float4 ho; ho.x = hn[0]; ho.y = hn[1]; ho.z = hn[2]; ho.w = hn[3];
    *(float4*)(out + ((long)m * T_ + t) * H_ + j) = ho;
    *(float4*)(hbuf + (long)m * H_ + j) = ho;
    *(ushort4*)(hbf + (long)m * H_ + j) = hb;
}

__global__ void sentinel_k(float* out) {
    if (threadIdx.x == 0 && blockIdx.x == 0) out[0] = 1.2345e8f;
}

extern "C" void kernel_launch(void* const* d_in, const int* in_sizes, int n_in,
                              void* d_out, int out_size, void* d_ws, size_t ws_size,
                              hipStream_t stream) {
    const float* dec  = (const float*)d_in[0];
    const float* enc  = (const float*)d_in[1];
    const float* h0   = (const float*)d_in[2];
    const float* Watt = (const float*)d_in[3];
    const float* Vatt = (const float*)d_in[4];
    const float* Wi   = (const float*)d_in[5];
    const float* Uh   = (const float*)d_in[6];
    const float* bias = (const float*)d_in[7];
    float* out = (float*)d_out;

    char* ws = (char*)d_ws;
    size_t off = 0;
    auto alloc = [&](size_t bytes) -> void* {
        void* p = ws + off;
        off += (bytes + 255) & ~(size_t)255;
        return p;
    };
    unsigned char*  P8    = (unsigned char*)alloc((size_t)32768 * 1024);        // 32 MB (fp8)
    unsigned char*  enc8  = (unsigned char*)alloc((size_t)33554432);            // 32 MB (fp8)
    unsigned short* decbf = (unsigned short*)alloc((size_t)4194304 * 2);        // 8 MB
    unsigned short* Xg    = (unsigned short*)alloc((size_t)4096 * 3072 * 2);    // 25 MB
    unsigned short* Wit1  = (unsigned short*)alloc((size_t)3072 * 1024 * 2);    // 6 MB
    unsigned short* Wit2  = (unsigned short*)alloc((size_t)3072 * 1024 * 2);    // 6 MB
    unsigned short* U4t   = (unsigned short*)alloc((size_t)4096 * 1024 * 2);    // 8 MB  [W1t | Uht]
    unsigned char*  W2t8  = (unsigned char*)alloc((size_t)1024 * 1024);         // 1 MB (fp8)
    unsigned short* hpart = (unsigned short*)alloc((size_t)4 * 128 * 4096 * 2); // 4 MB bf16 (q|rec)
    unsigned short* cpart = (unsigned short*)alloc((size_t)4 * 128 * 3072 * 2); // 3.1 MB bf16
    float* pctx  = (float*)alloc((size_t)8 * 128 * 1024 * 4);                   // 4 MB
    float* pml   = (float*)alloc((size_t)8 * 128 * 2 * 4);
    unsigned short* ctxbf = (unsigned short*)alloc((size_t)128 * 1024 * 2);
    float* hbuf  = (float*)alloc((size_t)128 * 1024 * 4);
    unsigned short* hbf = (unsigned short*)alloc((size_t)128 * 1024 * 2);

    if (off > ws_size) {  // scratch too small -> recognizable sentinel
        sentinel_k<<<1, 64, 0, stream>>>(out);
        return;
    }

    const float qscale = 2.0f * LOG2E;

    // ---- precompute ----
    conv_fp8<<<33554432 / 8 / 256, 256, 0, stream>>>(enc, enc8, 33554432);
    conv_bf16<<<4194304 / 8 / 256, 256, 0, stream>>>(dec, decbf, 4194304);
    init_h<<<512, 256, 0, stream>>>(h0, hbuf, hbf, 131072);
    // Wit1[n,k] = Wi[k,n] for k<1024 ; Wit2[n,k] = Wi[1024+k,n]
    transpose_conv<<<dim3(48, 16), 256, 0, stream>>>(Wi, 3072, Wit1, 1024, 1.0f);
    transpose_conv<<<dim3(48, 16), 256, 0, stream>>>(Wi + (size_t)1024 * 3072, 3072, Wit2, 1024, 1.0f);
    // U4t rows 0..1023 = (2log2e*W1)^T ; rows 1024..4095 = Uh^T
    transpose_conv<<<dim3(16, 16), 256, 0, stream>>>(Watt, 1024, U4t, 1024, qscale);
    transpose_conv<<<dim3(48, 16), 256, 0, stream>>>(Uh, 3072, U4t + (size_t)1024 * 1024, 1024, 1.0f);
    // W2t8 = fp8((2log2e * W_att rows 1024..2047)^T)
    transpose_conv_fp8<<<dim3(16, 16), 256, 0, stream>>>(Watt + (size_t)1024 * 1024, 1024, W2t8, 1024, qscale);
    // P8 = fp8(enc8 @ W2t8^T)  (prescaled, full fp8 pipeline)  [32768,1024]
    gemm128_f8<1><<<dim3(8, 256, 1), 256, 0, stream>>>(enc8, 1024, W2t8, 1024, P8, 1024, 1024);
    // Xg = dec_flat @ Wi1  [4096,3072] bf16 (time-invariant x-part of gates)
    gemm128<1><<<dim3(24, 32, 1), 256, 0, stream>>>(decbf, 1024, Wit1, 1024, Xg, 3072, 1024, 0);

    // ---- recurrence (5 launches/step) ----
    for (int t = 0; t < T_; t++) {
        // hpart = h @ [2log2e*W1 | Uh]  (split-K x4 bf16 partials, q in cols 0..1023)
        gemm128<0><<<dim3(32, 1, 4), 256, 0, stream>>>(hbf, 1024, U4t, 1024, hpart, 4096, 256,
                                                       (long)128 * 4096);
        attn_kernel<<<dim3(8, 128), 256, 0, stream>>>(P8, enc8, hpart, Vatt, pctx, pml);
        combine_ctx<<<128, 256, 0, stream>>>(pctx, pml, ctxbf);
        ctxgates<<<dim3(24, 1, 4), 256, 0, stream>>>(ctxbf, Wit2, cpart);
        gru_update<<<128, 256, 0, stream>>>(cpart, hpart, Xg, bias, hbuf, hbf, out, t);
    }
}

// Round 16
// 1399.924 us; speedup vs baseline: 1.0351x; 1.0351x over previous
//
#include <hip/hip_runtime.h>
#include <hip/hip_bf16.h>
#include <stdint.h>

#define B_ 128
#define T_ 32
#define S_ 256
#define H_ 1024
#define E_ 1024
#define LOG2E 1.4426950408889634f

typedef __attribute__((ext_vector_type(8))) short short8;
typedef __attribute__((ext_vector_type(4))) float f32x4;
typedef __attribute__((ext_vector_type(2))) float f32x2;

typedef const __attribute__((address_space(1))) unsigned int* gas_ptr;
typedef __attribute__((address_space(3))) unsigned int* las_ptr;

__device__ __forceinline__ void gl_lds16(const void* g, void* l) {
    __builtin_amdgcn_global_load_lds((gas_ptr)g, (las_ptr)l, 16, 0, 0);
}

__device__ __forceinline__ float bf2f(unsigned short u) {
    union { unsigned int i; float f; } v; v.i = ((unsigned int)u) << 16; return v.f;
}
__device__ __forceinline__ unsigned short f2bf(float f) {
    union { float f; unsigned int i; } v; v.f = f;
    unsigned int i = v.i;
    return (unsigned short)((i + 0x7FFFu + ((i >> 16) & 1u)) >> 16);
}
__device__ __forceinline__ unsigned char f2fp8(float f) {
    return (unsigned char)((unsigned int)__builtin_amdgcn_cvt_pk_fp8_f32(f, f, 0, false) & 0xFF);
}
__device__ __forceinline__ float fexp2(float x) { return __builtin_amdgcn_exp2f(x); }
__device__ __forceinline__ float frcp(float x)  { return __builtin_amdgcn_rcpf(x); }
__device__ __forceinline__ float fast_tanh(float x) {
    float e = fexp2(x * (2.0f * LOG2E));
    return 1.0f - 2.0f * frcp(e + 1.0f);
}
__device__ __forceinline__ float fast_sigmoid(float x) {
    return frcp(1.0f + fexp2(-LOG2E * x));
}

// ---------------- flat f32 -> bf16 convert (n multiple of 8) ----------------
__global__ __launch_bounds__(256) void conv_bf16(const float* __restrict__ src,
                                                 unsigned short* __restrict__ dst, long n) {
    long i = ((long)blockIdx.x * 256 + threadIdx.x) * 8;
    if (i >= n) return;
    float4 x = *(const float4*)(src + i);
    float4 y = *(const float4*)(src + i + 4);
    unsigned int w0 = (unsigned int)f2bf(x.x) | ((unsigned int)f2bf(x.y) << 16);
    unsigned int w1 = (unsigned int)f2bf(x.z) | ((unsigned int)f2bf(x.w) << 16);
    unsigned int w2 = (unsigned int)f2bf(y.x) | ((unsigned int)f2bf(y.y) << 16);
    unsigned int w3 = (unsigned int)f2bf(y.z) | ((unsigned int)f2bf(y.w) << 16);
    uint4 o; o.x = w0; o.y = w1; o.z = w2; o.w = w3;
    *(uint4*)(dst + i) = o;
}

// ---------------- flat f32 -> fp8-e4m3 convert (n multiple of 8) ----------------
__global__ __launch_bounds__(256) void conv_fp8(const float* __restrict__ src,
                                                unsigned char* __restrict__ dst, long n) {
    long i = ((long)blockIdx.x * 256 + threadIdx.x) * 8;
    if (i >= n) return;
    float4 x = *(const float4*)(src + i);
    float4 y = *(const float4*)(src + i + 4);
    unsigned int w0 = (unsigned int)__builtin_amdgcn_cvt_pk_fp8_f32(x.x, x.y, 0, false);
    w0 = (unsigned int)__builtin_amdgcn_cvt_pk_fp8_f32(x.z, x.w, (int)w0, true);
    unsigned int w1 = (unsigned int)__builtin_amdgcn_cvt_pk_fp8_f32(y.x, y.y, 0, false);
    w1 = (unsigned int)__builtin_amdgcn_cvt_pk_fp8_f32(y.z, y.w, (int)w1, true);
    uint2 o; o.x = w0; o.y = w1;
    *(uint2*)(dst + i) = o;
}

// ---------------- init h buffers ----------------
__global__ __launch_bounds__(256) void init_h(const float* __restrict__ h0,
                                              float* __restrict__ hbuf,
                                              unsigned short* __restrict__ hbf, int n) {
    int i = blockIdx.x * 256 + threadIdx.x;
    if (i < n) { float v = h0[i]; hbuf[i] = v; hbf[i] = f2bf(v); }
}

// ---------------- tiled transpose+convert+scale: dst[c, r] = bf16(scale*src[r, c]) ----------------
// grid: (C/64, R/64), block 256
__global__ __launch_bounds__(256) void transpose_conv(const float* __restrict__ src, int ldsrc,
                                                      unsigned short* __restrict__ dst, int lddst,
                                                      float scale) {
    __shared__ float tile[64][65];
    int tid = threadIdx.x;
    int c0 = blockIdx.x * 64, r0 = blockIdx.y * 64;
    int tr = tid >> 6, tc = tid & 63;
#pragma unroll
    for (int i = 0; i < 16; i++) {
        int r = i * 4 + tr;
        tile[r][tc] = src[(long)(r0 + r) * ldsrc + c0 + tc];
    }
    __syncthreads();
#pragma unroll
    for (int i = 0; i < 16; i++) {
        int rr = i * 4 + tr;
        dst[(long)(c0 + rr) * lddst + r0 + tc] = f2bf(scale * tile[tc][rr]);
    }
}

// ---------------- tiled transpose+convert+scale to fp8: dst[c, r] = fp8(scale*src[r, c]) ----------------
__global__ __launch_bounds__(256) void transpose_conv_fp8(const float* __restrict__ src, int ldsrc,
                                                          unsigned char* __restrict__ dst, int lddst,
                                                          float scale) {
    __shared__ float tile[64][65];
    int tid = threadIdx.x;
    int c0 = blockIdx.x * 64, r0 = blockIdx.y * 64;
    int tr = tid >> 6, tc = tid & 63;
#pragma unroll
    for (int i = 0; i < 16; i++) {
        int r = i * 4 + tr;
        tile[r][tc] = src[(long)(r0 + r) * ldsrc + c0 + tc];
    }
    __syncthreads();
#pragma unroll
    for (int i = 0; i < 16; i++) {
        int rr = i * 4 + tr;
        dst[(long)(c0 + rr) * lddst + r0 + tc] = f2fp8(scale * tile[tc][rr]);
    }
}

// ---------------- generic 128x128-tile bf16 MFMA GEMM (m97 structure) ----------------
// C[M,N] = A[M,K] @ Bt[N,K]^T ; A,Bt bf16 row-major. bf16 store (+ partStride per z).
// SWZ: XCD-chunked remap (requires (gx*gy)%8==0, z==1).
// grid: (N/128, M/128, ksplit). kLen = K chunk per z-block. partStride in ELEMENTS.
template <int SWZ>
__global__ __launch_bounds__(256) void gemm128(const unsigned short* __restrict__ A, int lda,
                                               const unsigned short* __restrict__ Bt, int ldb,
                                               unsigned short* __restrict__ Cout, int ldc,
                                               int kLen, long partStride) {
    __shared__ unsigned short As[128 * 32];
    __shared__ unsigned short Bs[128 * 32];
    const int tid = threadIdx.x;
    int lin = blockIdx.y * gridDim.x + blockIdx.x;
    if (SWZ) {
        int cpx = (gridDim.x * gridDim.y) >> 3;
        lin = (lin & 7) * cpx + (lin >> 3);
    }
    const int n0 = (lin % gridDim.x) * 128;
    const int m0 = (lin / gridDim.x) * 128;
    const int kStart = blockIdx.z * kLen;
    const int w = tid >> 6, l = tid & 63;
    const int wr = w >> 1, wc = w & 1;

    f32x4 acc[4][4];
#pragma unroll
    for (int i = 0; i < 4; i++)
#pragma unroll
        for (int j = 0; j < 4; j++) acc[i][j] = f32x4{0.f, 0.f, 0.f, 0.f};

    for (int kt = 0; kt < kLen; kt += 32) {
        int k0 = kStart + kt;
#pragma unroll
        for (int i = 0; i < 2; i++) {
            int f = i * 4096 + tid * 16;
            int row = f >> 6;
            int cb = f & 63;
            gl_lds16(A + (long)(m0 + row) * lda + k0 + (cb >> 1), (char*)As + f);
            gl_lds16(Bt + (long)(n0 + row) * ldb + k0 + (cb >> 1), (char*)Bs + f);
        }
        asm volatile("s_waitcnt vmcnt(0)" ::: "memory");
        __syncthreads();
        short8 a[4], b[4];
#pragma unroll
        for (int fi = 0; fi < 4; fi++) {
            a[fi] = *(const short8*)((const char*)As + ((wr * 64 + fi * 16 + (l & 15)) * 32 + ((l >> 4) * 8)) * 2);
            b[fi] = *(const short8*)((const char*)Bs + ((wc * 64 + fi * 16 + (l & 15)) * 32 + ((l >> 4) * 8)) * 2);
        }
#pragma unroll
        for (int fi = 0; fi < 4; fi++)
#pragma unroll
            for (int fj = 0; fj < 4; fj++)
                acc[fi][fj] = __builtin_amdgcn_mfma_f32_16x16x32_bf16(a[fi], b[fj], acc[fi][fj], 0, 0, 0);
        __syncthreads();
    }

    long cz = (long)blockIdx.z * partStride;
#pragma unroll
    for (int fi = 0; fi < 4; fi++)
#pragma unroll
        for (int fj = 0; fj < 4; fj++) {
            int m = m0 + wr * 64 + fi * 16 + ((l >> 4) << 2);
            int n = n0 + wc * 64 + fj * 16 + (l & 15);
#pragma unroll
            for (int r = 0; r < 4; r++)
                (Cout + cz)[(long)(m + r) * ldc + n] = f2bf(acc[fi][fj][r]);
        }
}

// ---------------- fp8 x fp8 128x128-tile GEMM (BK=64), fp8 output (for P) ----------------
// C[M,N] = A[M,K] @ Bt[N,K]^T ; A,Bt fp8-e4m3 row-major. grid (N/128, M/128).
// LDS slot-swizzle (both-sides): global source column pre-swizzled, ds_read swizzled.
template <int SWZ>
__global__ __launch_bounds__(256) void gemm128_f8(const unsigned char* __restrict__ A, int lda,
                                                  const unsigned char* __restrict__ Bt, int ldb,
                                                  unsigned char* __restrict__ Cout, int ldc,
                                                  int kLen) {
    __shared__ unsigned char As[128 * 64];
    __shared__ unsigned char Bs[128 * 64];
    const int tid = threadIdx.x;
    int lin = blockIdx.y * gridDim.x + blockIdx.x;
    if (SWZ) {
        int cpx = (gridDim.x * gridDim.y) >> 3;
        lin = (lin & 7) * cpx + (lin >> 3);
    }
    const int n0 = (lin % gridDim.x) * 128;
    const int m0 = (lin / gridDim.x) * 128;
    const int w = tid >> 6, l = tid & 63;
    const int wr = w >> 1, wc = w & 1;
    const int sx = (l & 6) << 3;            // read-side slot swizzle

    f32x4 acc[4][4];
#pragma unroll
    for (int i = 0; i < 4; i++)
#pragma unroll
        for (int j = 0; j < 4; j++) acc[i][j] = f32x4{0.f, 0.f, 0.f, 0.f};

    for (int k0 = 0; k0 < kLen; k0 += 64) {
#pragma unroll
        for (int i = 0; i < 2; i++) {
            int f = i * 4096 + tid * 16;
            int row = f >> 6;       // 64 B per row
            int cb = (f & 63) ^ ((row & 6) << 3);   // pre-swizzled global column
            gl_lds16(A + (long)(m0 + row) * lda + k0 + cb, (char*)As + f);
            gl_lds16(Bt + (long)(n0 + row) * ldb + k0 + cb, (char*)Bs + f);
        }
        asm volatile("s_waitcnt vmcnt(0)" ::: "memory");
        __syncthreads();
        long a[4][2], b[4][2];
#pragma unroll
        for (int fi = 0; fi < 4; fi++)
#pragma unroll
            for (int ks = 0; ks < 2; ks++) {
                int colb = (ks * 32 + ((l >> 4) * 8)) ^ sx;
                a[fi][ks] = *(const long*)(As + (wr * 64 + fi * 16 + (l & 15)) * 64 + colb);
                b[fi][ks] = *(const long*)(Bs + (wc * 64 + fi * 16 + (l & 15)) * 64 + colb);
            }
#pragma unroll
        for (int fi = 0; fi < 4; fi++)
#pragma unroll
            for (int fj = 0; fj < 4; fj++) {
                acc[fi][fj] = __builtin_amdgcn_mfma_f32_16x16x32_fp8_fp8(a[fi][0], b[fj][0], acc[fi][fj], 0, 0, 0);
                acc[fi][fj] = __builtin_amdgcn_mfma_f32_16x16x32_fp8_fp8(a[fi][1], b[fj][1], acc[fi][fj], 0, 0, 0);
            }
        __syncthreads();
    }

#pragma unroll
    for (int fi = 0; fi < 4; fi++)
#pragma unroll
        for (int fj = 0; fj < 4; fj++) {
            int m = m0 + wr * 64 + fi * 16 + ((l >> 4) << 2);
            int n = n0 + wc * 64 + fj * 16 + (l & 15);
#pragma unroll
            for (int r = 0; r < 4; r++)
                Cout[(long)(m + r) * ldc + n] = f2fp8(acc[fi][fj][r]);
        }
}

// ---------------- fused rec+ctx gates GEMM (bf16 partial slabs) ----------------
// grid (24, 2, 4): y=0 -> h@Uh^T, y=1 -> ctx@Wi2^T. Both M=128, N=3072, K=1024.
// Writes bf16 partials gpart[y*4+z][128][3072].
__global__ __launch_bounds__(256) void recgates(const unsigned short* __restrict__ hbf,
                                                const unsigned short* __restrict__ ctxbf,
                                                const unsigned short* __restrict__ Uht,
                                                const unsigned short* __restrict__ Wit2,
                                                unsigned short* __restrict__ gpart) {
    __shared__ unsigned short As[128 * 32];
    __shared__ unsigned short Bs[128 * 32];
    const int tid = threadIdx.x;
    const int n0 = blockIdx.x * 128;
    const int y = blockIdx.y, z = blockIdx.z;
    const unsigned short* A  = y ? ctxbf : hbf;
    const unsigned short* Bt = y ? Wit2 : Uht;
    const int kStart = z * 256;
    const int w = tid >> 6, l = tid & 63;
    const int wr = w >> 1, wc = w & 1;

    f32x4 acc[4][4];
#pragma unroll
    for (int i = 0; i < 4; i++)
#pragma unroll
        for (int j = 0; j < 4; j++) acc[i][j] = f32x4{0.f, 0.f, 0.f, 0.f};

    for (int kt = 0; kt < 256; kt += 32) {
        int k0 = kStart + kt;
#pragma unroll
        for (int i = 0; i < 2; i++) {
            int f = i * 4096 + tid * 16;
            int row = f >> 6;
            int cb = f & 63;
            gl_lds16(A + (long)row * 1024 + k0 + (cb >> 1), (char*)As + f);
            gl_lds16(Bt + (long)(n0 + row) * 1024 + k0 + (cb >> 1), (char*)Bs + f);
        }
        asm volatile("s_waitcnt vmcnt(0)" ::: "memory");
        __syncthreads();
        short8 a[4], b[4];
#pragma unroll
        for (int fi = 0; fi < 4; fi++) {
            a[fi] = *(const short8*)((const char*)As + ((wr * 64 + fi * 16 + (l & 15)) * 32 + ((l >> 4) * 8)) * 2);
            b[fi] = *(const short8*)((const char*)Bs + ((wc * 64 + fi * 16 + (l & 15)) * 32 + ((l >> 4) * 8)) * 2);
        }
#pragma unroll
        for (int fi = 0; fi < 4; fi++)
#pragma unroll
            for (int fj = 0; fj < 4; fj++)
                acc[fi][fj] = __builtin_amdgcn_mfma_f32_16x16x32_bf16(a[fi], b[fj], acc[fi][fj], 0, 0, 0);
        __syncthreads();
    }

    unsigned short* C = gpart + (long)(y * 4 + z) * (128 * 3072);
#pragma unroll
    for (int fi = 0; fi < 4; fi++)
#pragma unroll
        for (int fj = 0; fj < 4; fj++) {
            int m = wr * 64 + fi * 16 + ((l >> 4) << 2);
            int n = n0 + wc * 64 + fj * 16 + (l & 15);
#pragma unroll
            for (int r = 0; r < 4; r++)
                C[(long)(m + r) * 3072 + n] = f2bf(acc[fi][fj][r]);
        }
}

// ---------------- attention: scores (tanh, fp8 P) + partial softmax + partial context (fp8 enc) ----------------
// grid: (8, B), block 256. Each block handles 32 source rows. P8 and q prescaled by 2*log2(e).
__global__ __launch_bounds__(256) void attn_kernel(const unsigned char* __restrict__ P8,
                                                   const unsigned char* __restrict__ enc8,
                                                   const unsigned short* __restrict__ partq,  // [8][128][1024] bf16
                                                   const float* __restrict__ V,
                                                   float* __restrict__ pctx,   // [8][B][H]
                                                   float* __restrict__ pml) {  // [8][B][2]
    const int oct = blockIdx.x, b = blockIdx.y;
    const int tid = threadIdx.x, w = tid >> 6, l = tid & 63;
    __shared__ float qs[1024];
    __shared__ float sc[32];
    __shared__ float wgt[32];

    // cooperative q build (sum of 8 bf16 split-K partials)
    {
        int j = tid * 4;
        float s0 = 0.f, s1 = 0.f, s2 = 0.f, s3 = 0.f;
#pragma unroll
        for (int p = 0; p < 8; p++) {
            ushort4 v = *(const ushort4*)(partq + (long)p * (128 * 1024) + (long)b * 1024 + j);
            s0 += bf2f(v.x); s1 += bf2f(v.y); s2 += bf2f(v.z); s3 += bf2f(v.w);
        }
        qs[j] = s0; qs[j + 1] = s1; qs[j + 2] = s2; qs[j + 3] = s3;
    }
    __syncthreads();

    float q[16], nv2[16];
    float sv = 0.f;
#pragma unroll
    for (int ii = 0; ii < 4; ii++) {
        float4 qq = *(const float4*)(qs + l * 16 + ii * 4);
        float4 vv = *(const float4*)(V + l * 16 + ii * 4);
        q[ii * 4 + 0] = qq.x; q[ii * 4 + 1] = qq.y; q[ii * 4 + 2] = qq.z; q[ii * 4 + 3] = qq.w;
        nv2[ii * 4 + 0] = -2.f * vv.x; nv2[ii * 4 + 1] = -2.f * vv.y;
        nv2[ii * 4 + 2] = -2.f * vv.z; nv2[ii * 4 + 3] = -2.f * vv.w;
        sv += vv.x + vv.y + vv.z + vv.w;
    }

    const int s0 = oct * 32;
#pragma unroll 2
    for (int ss = 0; ss < 8; ss++) {
        int s = w * 8 + ss;
        const unsigned char* prow = P8 + ((long)(b * S_ + s0 + s)) * H_ + l * 16;
        uint4 pw = *(const uint4*)prow;
        float pv[16];
        {
            f32x2 d;
            d = __builtin_amdgcn_cvt_pk_f32_fp8(pw.x, false); pv[0] = d.x; pv[1] = d.y;
            d = __builtin_amdgcn_cvt_pk_f32_fp8(pw.x, true);  pv[2] = d.x; pv[3] = d.y;
            d = __builtin_amdgcn_cvt_pk_f32_fp8(pw.y, false); pv[4] = d.x; pv[5] = d.y;
            d = __builtin_amdgcn_cvt_pk_f32_fp8(pw.y, true);  pv[6] = d.x; pv[7] = d.y;
            d = __builtin_amdgcn_cvt_pk_f32_fp8(pw.z, false); pv[8] = d.x; pv[9] = d.y;
            d = __builtin_amdgcn_cvt_pk_f32_fp8(pw.z, true);  pv[10] = d.x; pv[11] = d.y;
            d = __builtin_amdgcn_cvt_pk_f32_fp8(pw.w, false); pv[12] = d.x; pv[13] = d.y;
            d = __builtin_amdgcn_cvt_pk_f32_fp8(pw.w, true);  pv[14] = d.x; pv[15] = d.y;
        }
        float acc = sv;
#pragma unroll
        for (int i = 0; i < 16; i++) {
            float x = q[i] + pv[i];             // prescaled by 2*log2e
            float d = frcp(fexp2(x) + 1.0f);
            acc = fmaf(d, nv2[i], acc);
        }
#pragma unroll
        for (int off = 32; off; off >>= 1) acc += __shfl_xor(acc, off);
        if (l == 0) sc[s] = acc;
    }
    __syncthreads();

    // partial softmax over the 32 local scores (each wave redundantly)
    float v = (l < 32) ? sc[l] : -3.4e38f;
    float mx = v;
#pragma unroll
    for (int off = 32; off; off >>= 1) mx = fmaxf(mx, __shfl_xor(mx, off));
    float ex = (l < 32) ? fexp2((v - mx) * LOG2E) : 0.f;
    float ls = ex;
#pragma unroll
    for (int off = 32; off; off >>= 1) ls += __shfl_xor(ls, off);
    if (tid < 32) wgt[tid] = ex;
    if (tid == 0) {
        pml[(oct * 128 + b) * 2 + 0] = mx;
        pml[(oct * 128 + b) * 2 + 1] = ls;
    }
    __syncthreads();

    // partial context: each thread owns 4 columns, 32 source rows (fp8 enc)
    float a0 = 0.f, a1 = 0.f, a2 = 0.f, a3 = 0.f;
    const unsigned char* ebase = enc8 + ((long)(b * S_ + s0)) * H_ + tid * 4;
#pragma unroll 4
    for (int s = 0; s < 32; s++) {
        float ws = wgt[s];
        unsigned int u = *(const unsigned int*)(ebase + (long)s * H_);
        f32x2 lo = __builtin_amdgcn_cvt_pk_f32_fp8(u, false);
        f32x2 hi = __builtin_amdgcn_cvt_pk_f32_fp8(u, true);
        a0 = fmaf(ws, lo.x, a0);
        a1 = fmaf(ws, lo.y, a1);
        a2 = fmaf(ws, hi.x, a2);
        a3 = fmaf(ws, hi.y, a3);
    }
    float* po = pctx + ((long)(oct * 128 + b)) * H_ + tid * 4;
    po[0] = a0; po[1] = a1; po[2] = a2; po[3] = a3;
}

// ---------------- combine the eight context partials -> ctx bf16 ----------------
__global__ __launch_bounds__(256) void combine_ctx(const float* __restrict__ pctx,
                                                   const float* __restrict__ pml,
                                                   unsigned short* __restrict__ ctxbf) {
    int b = blockIdx.x, tid = threadIdx.x;
    float mm[8], ll[8];
    float m = -3.4e38f;
#pragma unroll
    for (int p = 0; p < 8; p++) {
        mm[p] = pml[(p * 128 + b) * 2 + 0];
        ll[p] = pml[(p * 128 + b) * 2 + 1];
        m = fmaxf(m, mm[p]);
    }
    float denom = 0.f, f[8];
#pragma unroll
    for (int p = 0; p < 8; p++) { f[p] = fexp2((mm[p] - m) * LOG2E); denom += f[p] * ll[p]; }
    float inv = frcp(denom);
    float a0 = 0.f, a1 = 0.f, a2 = 0.f, a3 = 0.f;
#pragma unroll
    for (int p = 0; p < 8; p++) {
        float4 c = *(const float4*)(pctx + ((long)(p * 128 + b)) * H_ + tid * 4);
        a0 = fmaf(f[p], c.x, a0); a1 = fmaf(f[p], c.y, a1);
        a2 = fmaf(f[p], c.z, a2); a3 = fmaf(f[p], c.w, a3);
    }
    unsigned short* o = ctxbf + (long)b * H_ + tid * 4;
    o[0] = f2bf(a0 * inv); o[1] = f2bf(a1 * inv); o[2] = f2bf(a2 * inv); o[3] = f2bf(a3 * inv);
}

// ---------------- GRU gate math + state update (bf16 slabs) ----------------
// grid: 128 (one block per batch row), block 256 (4 cols per thread).
__global__ __launch_bounds__(256) void gru_update(const unsigned short* __restrict__ gpart,  // 8x[128,3072] bf16
                                                  const unsigned short* __restrict__ xg,  // [4096,3072] bf16
                                                  const float* __restrict__ bias,   // [3072]
                                                  float* __restrict__ hbuf,
                                                  unsigned short* __restrict__ hbf,
                                                  float* __restrict__ out, int t) {
    const int m = blockIdx.x;
    const int j = threadIdx.x * 4;
    const unsigned short* xr = xg + ((long)(m * T_ + t)) * 3072;
    ushort4 xz = *(const ushort4*)(xr + j);
    ushort4 xrr = *(const ushort4*)(xr + 1024 + j);
    ushort4 xh = *(const ushort4*)(xr + 2048 + j);
    float gz[4] = {bf2f(xz.x), bf2f(xz.y), bf2f(xz.z), bf2f(xz.w)};
    float gr[4] = {bf2f(xrr.x), bf2f(xrr.y), bf2f(xrr.z), bf2f(xrr.w)};
    float gh[4] = {bf2f(xh.x), bf2f(xh.y), bf2f(xh.z), bf2f(xh.w)};
    float rz[4] = {0, 0, 0, 0}, rr[4] = {0, 0, 0, 0}, rh[4] = {0, 0, 0, 0};
#pragma unroll
    for (int p = 0; p < 8; p++) {
        const unsigned short* gp = gpart + (long)p * (128 * 3072) + (long)m * 3072;
        ushort4 a = *(const ushort4*)(gp + j);
        ushort4 bb = *(const ushort4*)(gp + 1024 + j);
        ushort4 c = *(const ushort4*)(gp + 2048 + j);
        if (p < 4) {  // rec slabs
            rz[0] += bf2f(a.x); rz[1] += bf2f(a.y); rz[2] += bf2f(a.z); rz[3] += bf2f(a.w);
            rr[0] += bf2f(bb.x); rr[1] += bf2f(bb.y); rr[2] += bf2f(bb.z); rr[3] += bf2f(bb.w);
            rh[0] += bf2f(c.x); rh[1] += bf2f(c.y); rh[2] += bf2f(c.z); rh[3] += bf2f(c.w);
        } else {      // ctx-gate slabs
            gz[0] += bf2f(a.x); gz[1] += bf2f(a.y); gz[2] += bf2f(a.z); gz[3] += bf2f(a.w);
            gr[0] += bf2f(bb.x); gr[1] += bf2f(bb.y); gr[2] += bf2f(bb.z); gr[3] += bf2f(bb.w);
            gh[0] += bf2f(c.x); gh[1] += bf2f(c.y); gh[2] += bf2f(c.z); gh[3] += bf2f(c.w);
        }
    }
    float4 bz = *(const float4*)(bias + j);
    float4 br = *(const float4*)(bias + 1024 + j);
    float4 bh = *(const float4*)(bias + 2048 + j);
    float4 hv = *(const float4*)(hbuf + (long)m * H_ + j);
    float bzf[4] = {bz.x, bz.y, bz.z, bz.w};
    float brf[4] = {br.x, br.y, br.z, br.w};
    float bhf[4] = {bh.x, bh.y, bh.z, bh.w};
    float hf[4] = {hv.x, hv.y, hv.z, hv.w};
    float hn[4];
    ushort4 hb;
#pragma unroll
    for (int c = 0; c < 4; c++) {
        float z = fast_sigmoid(gz[c] + bzf[c] + rz[c]);
        float r = fast_sigmoid(gr[c] + brf[c] + rr[c]);
        float hh = fast_tanh(gh[c] + bhf[c] + r * rh[c]);
        hn[c] = z * hf[c] + (1.0f - z) * hh;
    }
    hb.x = f2bf(hn[0]); hb.y = f2bf(hn[1]); hb.z = f2bf(hn[2]); hb.w = f2bf(hn[3]);
    float4 ho; ho.x = hn[0]; ho.y = hn[1]; ho.z = hn[2]; ho.w = hn[3];
    *(float4*)(out + ((long)m * T_ + t) * H_ + j) = ho;
    *(float4*)(hbuf + (long)m * H_ + j) = ho;
    *(ushort4*)(hbf + (long)m * H_ + j) = hb;
}

__global__ void sentinel_k(float* out) {
    if (threadIdx.x == 0 && blockIdx.x == 0) out[0] = 1.2345e8f;
}

extern "C" void kernel_launch(void* const* d_in, const int* in_sizes, int n_in,
                              void* d_out, int out_size, void* d_ws, size_t ws_size,
                              hipStream_t stream) {
    const float* dec  = (const float*)d_in[0];
    const float* enc  = (const float*)d_in[1];
    const float* h0   = (const float*)d_in[2];
    const float* Watt = (const float*)d_in[3];
    const float* Vatt = (const float*)d_in[4];
    const float* Wi   = (const float*)d_in[5];
    const float* Uh   = (const float*)d_in[6];
    const float* bias = (const float*)d_in[7];
    float* out = (float*)d_out;

    char* ws = (char*)d_ws;
    size_t off = 0;
    auto alloc = [&](size_t bytes) -> void* {
        void* p = ws + off;
        off += (bytes + 255) & ~(size_t)255;
        return p;
    };
    unsigned char*  P8    = (unsigned char*)alloc((size_t)32768 * 1024);        // 32 MB (fp8)
    unsigned char*  enc8  = (unsigned char*)alloc((size_t)33554432);            // 32 MB (fp8)
    unsigned short* decbf = (unsigned short*)alloc((size_t)4194304 * 2);        // 8 MB
    unsigned short* Xg    = (unsigned short*)alloc((size_t)4096 * 3072 * 2);    // 25 MB
    unsigned short* Wit1  = (unsigned short*)alloc((size_t)3072 * 1024 * 2);    // 6 MB
    unsigned short* Wit2  = (unsigned short*)alloc((size_t)3072 * 1024 * 2);    // 6 MB
    unsigned short* Uht   = (unsigned short*)alloc((size_t)3072 * 1024 * 2);    // 6 MB
    unsigned short* W1t   = (unsigned short*)alloc((size_t)1024 * 1024 * 2);    // 2 MB
    unsigned char*  W2t8  = (unsigned char*)alloc((size_t)1024 * 1024);         // 1 MB (fp8)
    unsigned short* partq = (unsigned short*)alloc((size_t)8 * 128 * 1024 * 2); // 2 MB bf16
    unsigned short* gpart = (unsigned short*)alloc((size_t)8 * 128 * 3072 * 2); // 6.3 MB bf16
    float* pctx  = (float*)alloc((size_t)8 * 128 * 1024 * 4);                   // 4 MB
    float* pml   = (float*)alloc((size_t)8 * 128 * 2 * 4);
    unsigned short* ctxbf = (unsigned short*)alloc((size_t)128 * 1024 * 2);
    float* hbuf  = (float*)alloc((size_t)128 * 1024 * 4);
    unsigned short* hbf = (unsigned short*)alloc((size_t)128 * 1024 * 2);

    if (off > ws_size) {  // scratch too small -> recognizable sentinel
        sentinel_k<<<1, 64, 0, stream>>>(out);
        return;
    }

    const float qscale = 2.0f * LOG2E;

    // ---- precompute ----
    conv_fp8<<<33554432 / 8 / 256, 256, 0, stream>>>(enc, enc8, 33554432);
    conv_bf16<<<4194304 / 8 / 256, 256, 0, stream>>>(dec, decbf, 4194304);
    init_h<<<512, 256, 0, stream>>>(h0, hbuf, hbf, 131072);
    // Wit1[n,k] = Wi[k,n] for k<1024 ; Wit2[n,k] = Wi[1024+k,n]
    transpose_conv<<<dim3(48, 16), 256, 0, stream>>>(Wi, 3072, Wit1, 1024, 1.0f);
    transpose_conv<<<dim3(48, 16), 256, 0, stream>>>(Wi + (size_t)1024 * 3072, 3072, Wit2, 1024, 1.0f);
    // Uht = Uh^T ; W1t = (2log2e * W_att rows 0..1023)^T ; W2t8 = fp8((2log2e * rows 1024..2047)^T)
    transpose_conv<<<dim3(48, 16), 256, 0, stream>>>(Uh, 3072, Uht, 1024, 1.0f);
    transpose_conv<<<dim3(16, 16), 256, 0, stream>>>(Watt, 1024, W1t, 1024, qscale);
    transpose_conv_fp8<<<dim3(16, 16), 256, 0, stream>>>(Watt + (size_t)1024 * 1024, 1024, W2t8, 1024, qscale);
    // P8 = fp8(enc8 @ W2t8^T)  (prescaled, full fp8 pipeline)  [32768,1024]
    gemm128_f8<1><<<dim3(8, 256, 1), 256, 0, stream>>>(enc8, 1024, W2t8, 1024, P8, 1024, 1024);
    // Xg = dec_flat @ Wi1  [4096,3072] bf16 (time-invariant x-part of gates)
    gemm128<1><<<dim3(24, 32, 1), 256, 0, stream>>>(decbf, 1024, Wit1, 1024, Xg, 3072, 1024, 0);

    // ---- recurrence (5 launches/step, round-13 structure) ----
    for (int t = 0; t < T_; t++) {
        // q = h @ (2log2e*W1)  (split-K x8 bf16 partials) — only blocker for attn
        gemm128<0><<<dim3(8, 1, 8), 256, 0, stream>>>(hbf, 1024, W1t, 1024, partq, 1024, 128,
                                                      (long)128 * 1024);
        attn_kernel<<<dim3(8, 128), 256, 0, stream>>>(P8, enc8, partq, Vatt, pctx, pml);
        combine_ctx<<<128, 256, 0, stream>>>(pctx, pml, ctxbf);
        recgates<<<dim3(24, 2, 4), 256, 0, stream>>>(hbf, ctxbf, Uht, Wit2, gpart);
        gru_update<<<128, 256, 0, stream>>>(gpart, Xg, bias, hbuf, hbf, out, t);
    }
}